// Round 18
// baseline (584.270 us; speedup 1.0000x reference)
//
#include <hip/hip_runtime.h>

// Problem constants
#define Bz 2048
#define Tz 336
#define Fz 10
#define H1 70
#define H2 21

typedef __attribute__((ext_vector_type(8))) short short8;   // 8 bf16 = 4 VGPR
typedef __attribute__((ext_vector_type(4))) float float4v;  // MFMA acc

#define MFMA16(a, b, c) __builtin_amdgcn_mfma_f32_16x16x32_bf16((a), (b), (c), 0, 0, 0)

// LDS-only barrier (composable-kernel idiom): orders LDS across the block
// WITHOUT draining vmcnt — __syncthreads() would stall on the y1/y2 global
// stores (never read in-kernel) every step (~200-900 cyc store-ack, m126).
__device__ __forceinline__ void sync_lds() {
    asm volatile("s_waitcnt lgkmcnt(0)\n\ts_barrier" ::: "memory");
}

// Manual RNE f32->bf16 (validated). r14: v_cvt_pk_bf16_f32 regressed absmax
// 10x (biased rounding compounds through the 336-step recurrence).
__device__ __forceinline__ unsigned short f2bf(float v) {
    unsigned int u = __float_as_uint(v);
    u += 0x7FFFu + ((u >> 16) & 1u);
    return (unsigned short)(u >> 16);
}
__device__ __forceinline__ float bf2f(unsigned short s) {
    return __uint_as_float(((unsigned int)s) << 16);
}

// [r12-VALIDATED gate epilogue — exp-domain, true division.]
// r14/r15/r17 bisect: exp2-domain weights + raw v_rcp regressed absmax to
// ~9e-3 (mechanism unexplained after audit) — RETIRED. This form measured
// absmax 0.98e-3 over many rounds.
//   cn = sig(f)*c + sig(i)*tanh(g);  h = sig(o)*tanh(cn)
// via a=e^-f, b=e^-i, d=e^2g:  cn = (c*pb*pd + pa*(d-1)) / (pa*pb*pd)
// 5 exp + 2 true divisions (common-denominator form).
__device__ __forceinline__ float lstm_gate_h(float gi, float gf, float gc,
                                             float go, float& cst) {
    float a  = __expf(-gf);
    float b  = __expf(-gi);
    float d  = __expf(2.0f * gc);
    float pa = 1.0f + a;
    float pb = 1.0f + b;
    float pd = d + 1.0f;
    float t1 = pb * pd;
    float num = fmaf(pa, d - 1.0f, cst * t1);
    float cn  = num / (pa * t1);
    float e2  = __expf(-go);
    float f2  = __expf(2.0f * cn);
    float h   = (f2 - 1.0f) / ((1.0f + e2) * (f2 + 1.0f));
    cst = cn;
    return h;
}

// Fragment-order LDS offset (in shorts) for (col m, k):
// (m, k) lives at ((k>>3)*16 + m)*8 + (k&7)
__device__ __forceinline__ int frag_off(int m, int k) {
    return (k >> 3) * 128 + m * 8 + (k & 7);
}

// ---------------------------------------------------------------------------
// Layer 1 (MFMA, D = W x h): input F=10, hidden 70.
// [UNCHANGED from r17 — measured 296.4 us, absmax 0.98e-3]
// Grid 256 = 2 dir x 128 tiles of 16 batch rows. 1024 threads = 16 waves.
// 18 M-tiles: wave w owns tile w; waves 0,1 also own tiles 16,17.
//   K: 0..69 = h, 70..79 = x, 80 = bias slot (B col 1.0), 81..95 = 0.
// y1 layout: [T][128][2304] bf16, frag-ordered for k=32..171 (slot =
// frag_off(n, 32+dir*70+u) - 512); k=172..175 slots are holes (lstm2 masks).
// ---------------------------------------------------------------------------
__global__ __launch_bounds__(1024, 4) void k_lstm1(
    const float* __restrict__ x,
    const float* __restrict__ wih_f, const float* __restrict__ whh_f,
    const float* __restrict__ bih_f, const float* __restrict__ bhh_f,
    const float* __restrict__ wih_b, const float* __restrict__ whh_b,
    const float* __restrict__ bih_b, const float* __restrict__ bhh_b,
    unsigned short* __restrict__ y1)
{
    __shared__ short hB_hi[2][1536];   // 96 k x 16 batch, frag order, dbuf

    const int tb  = blockIdx.x & 127;
    const int dir = blockIdx.x >> 7;
    const int b0  = tb << 4;
    const float* wih = dir ? wih_b : wih_f;
    const float* whh = dir ? whh_b : whh_f;
    const float* bih = dir ? bih_b : bih_f;
    const float* bhh = dir ? bhh_b : bhh_f;

    const int tid  = threadIdx.x;
    const int wv   = tid >> 6;
    const int lane = tid & 63;
    const int n    = lane & 15;
    const int quad = lane >> 4;
    const int NT1  = (wv < 2) ? 2 : 1;   // tiles this wave owns

    // ---- W-side (A-operand) preload, hi+lo bf16 ----
    short8 whi[2][3], wlo[2][3];
    const int g_ = n & 3;                               // 0=i 1=f 2=g 3=o
#pragma unroll
    for (int tt = 0; tt < 2; ++tt) {
        if (tt < NT1) {
            const int p  = wv + 16 * tt;
            const int uu = 4 * p + (n >> 2);
#pragma unroll
            for (int q = 0; q < 3; ++q) {
#pragma unroll
                for (int j = 0; j < 8; ++j) {
                    int k = q * 32 + quad * 8 + j;
                    float v = 0.0f;
                    if (uu < H1) {
                        int row = g_ * H1 + uu;
                        if (k < H1)        v = whh[row * H1 + k];
                        else if (k < 80)   v = wih[row * Fz + (k - H1)];
                        else if (k == 80)  v = bih[row] + bhh[row];
                    }
                    unsigned short hi = f2bf(v);
                    unsigned short lo = f2bf(v - bf2f(hi));
                    whi[tt][q][j] = (short)hi;
                    wlo[tt][q][j] = (short)lo;
                }
            }
        }
    }

    // ---- init LDS ----
    for (int e = tid; e < 1536; e += 1024) {
        hB_hi[0][e] = 0; hB_hi[1][e] = 0;
    }
    __syncthreads();
    if (tid < 16) {
        int off = 1280 + tid * 8;       // frag_off(tid, 80)
        hB_hi[0][off] = (short)0x3F80;  // bf16(1.0) bias const
        hB_hi[1][off] = (short)0x3F80;
    }

    // ---- stagers: es in [0,160) -> (m, f), threads 864..1023 ----
    const int es = tid - 864;
    const bool stg = (es >= 0 && es < 160);
    int sm = 0, sf = 0;
    if (stg) { sm = es / Fz; sf = es % Fz; }

    const int tstep = dir ? -1 : 1;
    const int t0    = dir ? (Tz - 1) : 0;

    // prologue: stage x(t0) into buf 0; preload x(t1) into regs
    float xv = 0.0f;
    if (stg) {
        float v = x[((size_t)(b0 + sm) * Tz + t0) * Fz + sf];
        hB_hi[0][frag_off(sm, H1 + sf)] = (short)f2bf(v);
        xv = x[((size_t)(b0 + sm) * Tz + t0 + tstep) * Fz + sf];
    }
    // strided pointers (advance by tstep*stride per step)
    const float* xp = x + ((size_t)(b0 + sm) * Tz + t0 + 2 * tstep) * Fz + sf;
    const ptrdiff_t xinc = (ptrdiff_t)tstep * Fz;
    unsigned short* ypB = y1 + (size_t)(t0 * 128 + tb) * 2304;
    const ptrdiff_t yinc = (ptrdiff_t)tstep * (128 * 2304);

    // hoisted LDS/global write offsets (loop-invariant)
    const int xoff = frag_off(sm, H1 + sf);
    int hoff[2], yoff[2];
#pragma unroll
    for (int tt = 0; tt < 2; ++tt) {
        const int u = 4 * (wv + 16 * tt) + quad;
        hoff[tt] = frag_off(n, u);
        const int K = 32 + dir * H1 + u;               // lstm2 frag k-index
        yoff[tt] = ((K >> 3) * 16 + n) * 8 + (K & 7) - 512;
    }

    float cst[2];
    cst[0] = 0.0f; cst[1] = 0.0f;

    // one step; pp is a literal at each call site -> all LDS addrs invariant
    auto body = [&](int step, const int pp) __attribute__((always_inline)) {
        sync_lds();   // buf[pp] complete, buf[pp^1] free (LDS-only barrier)

        if (stg && step + 1 < Tz) {
            hB_hi[pp ^ 1][xoff] = (short)f2bf(xv);
        }
        if (stg && step + 2 < Tz) {
            xv = *xp;
        }

        short8 bhi[3];
#pragma unroll
        for (int q = 0; q < 3; ++q)
            bhi[q] = *(const short8*)&hB_hi[pp][q * 512 + lane * 8];

        // merged hi/lo chain: single acc per tile
        float4v acc[2];
#pragma unroll
        for (int tt = 0; tt < 2; ++tt) acc[tt] = (float4v){0.f, 0.f, 0.f, 0.f};
#pragma unroll
        for (int tt = 0; tt < 2; ++tt) {
            if (tt < NT1) {
                acc[tt] = MFMA16(whi[tt][0], bhi[0], acc[tt]);
                acc[tt] = MFMA16(wlo[tt][0], bhi[0], acc[tt]);
                acc[tt] = MFMA16(whi[tt][1], bhi[1], acc[tt]);
                acc[tt] = MFMA16(wlo[tt][1], bhi[1], acc[tt]);
                acc[tt] = MFMA16(whi[tt][2], bhi[2], acc[tt]);
                acc[tt] = MFMA16(wlo[tt][2], bhi[2], acc[tt]);
            }
        }

#pragma unroll
        for (int tt = 0; tt < 2; ++tt) {
            if (tt < NT1) {
                const int u = 4 * (wv + 16 * tt) + quad;
                if (u < H1) {
                    float h = lstm_gate_h(acc[tt][0], acc[tt][1],
                                          acc[tt][2], acc[tt][3], cst[tt]);
                    unsigned short hh = f2bf(h);
                    hB_hi[pp ^ 1][hoff[tt]] = (short)hh;
                    ypB[yoff[tt]] = hh;
                }
            }
        }
        xp  += xinc;
        ypB += yinc;
    };

    for (int step = 0; step < Tz; step += 2) {
        body(step, 0);
        body(step + 1, 1);
    }
}

// ---------------------------------------------------------------------------
// Layer 2 (MFMA, D = W x h): input 140 (bf16 y1 [T][128][2304] FRAG-ORDER),
// hidden 21.  [round-18: x-part OFF the recurrence path]
// r17 analysis: lstm2 is LATENCY-bound (step ~1808 cyc, issue only ~300);
// critical path = stager LDS write -> 6 ds_read -> 7-dep MFMA -> epilogue.
// But 5 of 7 MFMAs (x-part, K=32..191) don't depend on h(t-1), and y1 is
// already frag-ordered -> each compute wave loads its x B-fragments DIRECTLY
// from global into registers, prefetched 2 steps ahead (all timesteps of y1
// exist before launch). Stagers eliminated; LDS holds only the h chunk
// (k=0..31). Step: barrier -> [1 ds_read || 5 x-MFMAs from regs] ->
// 2 h-MFMAs -> epilogue -> h ds_write -> barrier. All 6 waves read the same
// 4.5KB/step of y1 -> L1 absorbs the 6x re-read (no HBM amplification).
// Chunk-5 tail (frag k>=172 = workspace holes/next-row garbage) masked by a
// per-lane AND mask (NaN guard; W rows there are 0 but 0*NaN=NaN).
// Grid 256 = 2 dir x 128 tiles of 16 rows. 384 thr = 6 waves, all compute
// (tile wv, u = 4wv+quad, u<21). K: 0..20 = h, 21 = bias, 32..171 = x.
// ---------------------------------------------------------------------------
__global__ __launch_bounds__(384, 2) void k_lstm2(
    const unsigned short* __restrict__ y1,
    const float* __restrict__ wih_f, const float* __restrict__ whh_f,
    const float* __restrict__ bih_f, const float* __restrict__ bhh_f,
    const float* __restrict__ wih_b, const float* __restrict__ whh_b,
    const float* __restrict__ bih_b, const float* __restrict__ bhh_b,
    unsigned short* __restrict__ y2)   // [B][T][42] bf16
{
    __shared__ short hH[2][512];   // k-chunk 0 only (h 0..20, bias 21, 0s), dbuf

    const int tb  = blockIdx.x & 127;
    const int dir = blockIdx.x >> 7;
    const int b0  = tb << 4;
    const float* wih = dir ? wih_b : wih_f;
    const float* whh = dir ? whh_b : whh_f;
    const float* bih = dir ? bih_b : bih_f;
    const float* bhh = dir ? bhh_b : bhh_f;

    const int tid  = threadIdx.x;
    const int wv   = tid >> 6;          // 0..5 — all waves compute
    const int lane = tid & 63;
    const int n    = lane & 15;
    const int quad = lane >> 4;

    // ---- W-side preload: hi all chunks, lo chunk 0 (r12/r17 numerics) ----
    short8 whi[6], wlo0;
    const int g_ = n & 3;
    {
        const int uu = 4 * wv + (n >> 2);
#pragma unroll
        for (int q = 0; q < 6; ++q) {
#pragma unroll
            for (int j = 0; j < 8; ++j) {
                int k = q * 32 + quad * 8 + j;
                float v = 0.0f;
                if (uu < H2) {
                    int row = g_ * H2 + uu;
                    if (k < H2)                   v = whh[row * H2 + k];
                    else if (k == 21)             v = bih[row] + bhh[row];
                    else if (k >= 32 && k < 172)  v = wih[row * 140 + (k - 32)];
                }
                unsigned short hi = f2bf(v);
                whi[q][j] = (short)hi;
                if (q == 0) wlo0[j] = (short)f2bf(v - bf2f(hi));
            }
        }
    }

    // ---- chunk-5 kill mask: frag element j dead iff 160 + quad*8+j >= 172 ----
    unsigned int kmask[4];
#pragma unroll
    for (int w2 = 0; w2 < 4; ++w2) {
        unsigned int m0 = (quad * 8 + 2 * w2     >= 12) ? 0u : 0xFFFFu;
        unsigned int m1 = (quad * 8 + 2 * w2 + 1 >= 12) ? 0u : 0xFFFFu;
        kmask[w2] = m0 | (m1 << 16);
    }

    // ---- init LDS (h(-1)=0; bias=1.0 at k=21 in both buffers) ----
    for (int e = tid; e < 512; e += 384) { hH[0][e] = 0; hH[1][e] = 0; }
    __syncthreads();
    if (tid < 16) {
        int off = frag_off(tid, 21);
        hH[0][off] = (short)0x3F80;
        hH[1][off] = (short)0x3F80;
    }

    const int tstep = dir ? -1 : 1;
    const int t0    = dir ? (Tz - 1) : 0;

    // ---- x prefetch: 5 B-fragments (chunks K=1..5) per step, depth 2 ----
    short8 xg0[5], xg1[5];
    {
        const unsigned short* r0p = y1 + ((size_t)t0 * 128 + tb) * 2304 + lane * 8;
        const unsigned short* r1p = y1 + ((size_t)(t0 + tstep) * 128 + tb) * 2304 + lane * 8;
#pragma unroll
        for (int q = 0; q < 5; ++q) {
            xg0[q] = *(const short8*)(r0p + q * 512);
            xg1[q] = *(const short8*)(r1p + q * 512);
        }
    }
    // srcp: row for step+2, advanced once per body
    const unsigned short* srcp =
        y1 + ((size_t)(t0 + 2 * tstep) * 128 + tb) * 2304 + lane * 8;
    const ptrdiff_t sinc = (ptrdiff_t)tstep * (128 * 2304);
    unsigned short* yp2 = y2 + ((size_t)(b0 + n) * Tz + t0) * 42 + dir * H2;
    const ptrdiff_t yinc = (ptrdiff_t)tstep * 42;

    const int u     = 4 * wv + quad;
    const int hoffc = frag_off(n, (u < H2) ? u : 0);

    float cst = 0.0f;

    auto body = [&](int step, const int pp, short8 (&xg)[5])
        __attribute__((always_inline)) {
        sync_lds();   // hH[pp] (h for this step) complete

        // issue the single h ds_read early; its latency hides under x-MFMAs
        short8 bhi0 = *(const short8*)&hH[pp][lane * 8];

        // masked chunk-5 operand (kill frag k>=172 garbage)
        short8 x4 = xg[4];
        {
            unsigned int* xw = (unsigned int*)&x4;
            xw[0] &= kmask[0]; xw[1] &= kmask[1];
            xw[2] &= kmask[2]; xw[3] &= kmask[3];
        }

        // x-part MFMAs — independent of the recurrence
        float4v acc = (float4v){0.f, 0.f, 0.f, 0.f};
        acc = MFMA16(whi[1], xg[0], acc);
        acc = MFMA16(whi[2], xg[1], acc);
        acc = MFMA16(whi[3], xg[2], acc);
        acc = MFMA16(whi[4], xg[3], acc);
        acc = MFMA16(whi[5], x4,    acc);

        // prefetch x for step+2 into the just-consumed registers
        if (step + 2 < Tz) {
#pragma unroll
            for (int q = 0; q < 5; ++q)
                xg[q] = *(const short8*)(srcp + q * 512);
        }

        // h-part (recurrence-critical): 2 MFMAs on the fresh h fragment
        acc = MFMA16(whi[0], bhi0, acc);
        acc = MFMA16(wlo0,   bhi0, acc);

        float h = lstm_gate_h(acc[0], acc[1], acc[2], acc[3], cst);
        unsigned short hh = f2bf(h);
        if (u < H2) {
            hH[pp ^ 1][hoffc] = (short)hh;
            yp2[u] = hh;
        }
        srcp += sinc;
        yp2  += yinc;
    };

    for (int step = 0; step < Tz; step += 2) {
        body(step,     0, xg0);
        body(step + 1, 1, xg1);
    }
}

// ---------------------------------------------------------------------------
// Dense head: thread per (b,t). Weights via uniform scalar loads.
// ---------------------------------------------------------------------------
__global__ __launch_bounds__(256) void k_dense(
    const unsigned short* __restrict__ y2,
    const float* __restrict__ wd1, const float* __restrict__ bd1,
    const float* __restrict__ wd2, const float* __restrict__ bd2,
    const float* __restrict__ wo,  const float* __restrict__ bo,
    float* __restrict__ out)
{
    int idx = blockIdx.x * 256 + threadIdx.x;
    if (idx >= Bz * Tz) return;
    const unsigned int* row = (const unsigned int*)&y2[(size_t)idx * 42];

    float v[42];
#pragma unroll
    for (int j = 0; j < 21; ++j) {
        unsigned int p = row[j];
        v[2 * j]     = bf2f((unsigned short)(p & 0xFFFFu));
        v[2 * j + 1] = bf2f((unsigned short)(p >> 16));
    }

    float h1[30];
#pragma unroll
    for (int o = 0; o < 30; ++o) {
        float s = bd1[o];
#pragma unroll
        for (int j = 0; j < 42; ++j) s = fmaf(v[j], wd1[o * 42 + j], s);
        h1[o] = fmaxf(s, 0.0f);
    }
    float outv = bo[0];
#pragma unroll
    for (int o = 0; o < 20; ++o) {
        float s = bd2[o];
#pragma unroll
        for (int j = 0; j < 30; ++j) s = fmaf(h1[j], wd2[o * 30 + j], s);
        outv = fmaf(fmaxf(s, 0.0f), wo[o], outv);
    }
    out[idx] = outv;
}

// ---------------------------------------------------------------------------
extern "C" void kernel_launch(void* const* d_in, const int* in_sizes, int n_in,
                              void* d_out, int out_size, void* d_ws, size_t ws_size,
                              hipStream_t stream)
{
    const float* x      = (const float*)d_in[0];
    const float* w1f_ih = (const float*)d_in[1];
    const float* w1f_hh = (const float*)d_in[2];
    const float* b1f_ih = (const float*)d_in[3];
    const float* b1f_hh = (const float*)d_in[4];
    const float* w1b_ih = (const float*)d_in[5];
    const float* w1b_hh = (const float*)d_in[6];
    const float* b1b_ih = (const float*)d_in[7];
    const float* b1b_hh = (const float*)d_in[8];
    const float* w2f_ih = (const float*)d_in[9];
    const float* w2f_hh = (const float*)d_in[10];
    const float* b2f_ih = (const float*)d_in[11];
    const float* b2f_hh = (const float*)d_in[12];
    const float* w2b_ih = (const float*)d_in[13];
    const float* w2b_hh = (const float*)d_in[14];
    const float* b2b_ih = (const float*)d_in[15];
    const float* b2b_hh = (const float*)d_in[16];
    const float* wd1    = (const float*)d_in[17];
    const float* bd1    = (const float*)d_in[18];
    const float* wd2    = (const float*)d_in[19];
    const float* bd2    = (const float*)d_in[20];
    const float* wo     = (const float*)d_in[21];
    const float* bo     = (const float*)d_in[22];
    float* out = (float*)d_out;

    // Workspace: y1 bf16 [T][128][2304] frag-order (198.2 MB)
    //          + y2 bf16 [B][T][42] (57.8 MB)
    const size_t y1_elems = (size_t)Tz * 128 * 2304;
    const size_t y2_elems = (size_t)Bz * Tz * 42;
    if (ws_size < (y1_elems + y2_elems) * 2) return;

    unsigned short* y1 = (unsigned short*)d_ws;
    unsigned short* y2 = y1 + y1_elems;

    hipLaunchKernelGGL(k_lstm1, dim3(256), dim3(1024), 0, stream,
                       x, w1f_ih, w1f_hh, b1f_ih, b1f_hh,
                       w1b_ih, w1b_hh, b1b_ih, b1b_hh, y1);
    hipLaunchKernelGGL(k_lstm2, dim3(256), dim3(384), 0, stream,
                       y1, w2f_ih, w2f_hh, b2f_ih, b2f_hh,
                       w2b_ih, w2b_hh, b2b_ih, b2b_hh, y2);
    hipLaunchKernelGGL(k_dense, dim3((Bz * Tz + 255) / 256), dim3(256), 0, stream,
                       y2, wd1, bd1, wd2, bd2, wo, bo, out);
}

// Round 19
// 580.880 us; speedup vs baseline: 1.0058x; 1.0058x over previous
//
#include <hip/hip_runtime.h>

// Problem constants
#define Bz 2048
#define Tz 336
#define Fz 10
#define H1 70
#define H2 21

typedef __attribute__((ext_vector_type(8))) short short8;   // 8 bf16 = 4 VGPR
typedef __attribute__((ext_vector_type(4))) float float4v;  // MFMA acc

#define MFMA16(a, b, c) __builtin_amdgcn_mfma_f32_16x16x32_bf16((a), (b), (c), 0, 0, 0)

// LDS-only barrier (composable-kernel idiom): orders LDS across the block
// WITHOUT draining vmcnt — __syncthreads() would stall on the y1/y2 global
// stores (never read in-kernel) every step (~200-900 cyc store-ack, m126).
__device__ __forceinline__ void sync_lds() {
    asm volatile("s_waitcnt lgkmcnt(0)\n\ts_barrier" ::: "memory");
}

// Manual RNE f32->bf16 (validated). r14: v_cvt_pk_bf16_f32 regressed absmax
// 10x (biased rounding compounds through the 336-step recurrence).
__device__ __forceinline__ unsigned short f2bf(float v) {
    unsigned int u = __float_as_uint(v);
    u += 0x7FFFu + ((u >> 16) & 1u);
    return (unsigned short)(u >> 16);
}
__device__ __forceinline__ float bf2f(unsigned short s) {
    return __uint_as_float(((unsigned int)s) << 16);
}

// [r12-VALIDATED gate epilogue — exp-domain, true division.]
// r14/r15/r17 bisect: exp2-domain weights + raw v_rcp regressed absmax to
// ~9e-3 — RETIRED. This form measured absmax 0.98e-3 over many rounds.
//   cn = sig(f)*c + sig(i)*tanh(g);  h = sig(o)*tanh(cn)
// via a=e^-f, b=e^-i, d=e^2g:  cn = (c*pb*pd + pa*(d-1)) / (pa*pb*pd)
// 5 exp + 2 true divisions (common-denominator form).
__device__ __forceinline__ float lstm_gate_h(float gi, float gf, float gc,
                                             float go, float& cst) {
    float a  = __expf(-gf);
    float b  = __expf(-gi);
    float d  = __expf(2.0f * gc);
    float pa = 1.0f + a;
    float pb = 1.0f + b;
    float pd = d + 1.0f;
    float t1 = pb * pd;
    float num = fmaf(pa, d - 1.0f, cst * t1);
    float cn  = num / (pa * t1);
    float e2  = __expf(-go);
    float f2  = __expf(2.0f * cn);
    float h   = (f2 - 1.0f) / ((1.0f + e2) * (f2 + 1.0f));
    cst = cn;
    return h;
}

// Fragment-order LDS offset (in shorts) for (col m, k):
// (m, k) lives at ((k>>3)*16 + m)*8 + (k&7)
__device__ __forceinline__ int frag_off(int m, int k) {
    return (k >> 3) * 128 + m * 8 + (k & 7);
}

// ---------------------------------------------------------------------------
// Layer 1 (MFMA, D = W x h): input F=10, hidden 70.
// [r17 structure + SPLIT MFMA chain (round-19's single change)]
// r17 counters: MfmaUtil 22.3% x 2116 cyc = 472 MFMA-pipe cyc/SIMD/step vs
// ~131 cyc physical -> the 6-deep merged hi/lo chain (an un-isolated part of
// r12's bundle) holds the pipe and delays the epilogue. Split back into two
// parallel 3-deep chains (accA=hi, accB=lo) + 4 fp32 adds: dependent depth
// halves, +8 VALU ops/tile. Reassociation at fp32-acc level only (~2^-24).
// Grid 256 = 2 dir x 128 tiles of 16 batch rows. 1024 threads = 16 waves.
// 18 M-tiles: wave w owns tile w; waves 0,1 also own tiles 16,17.
//   K: 0..69 = h, 70..79 = x, 80 = bias slot (B col 1.0), 81..95 = 0.
// y1 layout: [T][128][2304] bf16, frag-ordered for k=32..171 (slot =
// frag_off(n, 32+dir*70+u) - 512); k=172..175 slots are holes (lstm2 zeros).
// ---------------------------------------------------------------------------
__global__ __launch_bounds__(1024, 4) void k_lstm1(
    const float* __restrict__ x,
    const float* __restrict__ wih_f, const float* __restrict__ whh_f,
    const float* __restrict__ bih_f, const float* __restrict__ bhh_f,
    const float* __restrict__ wih_b, const float* __restrict__ whh_b,
    const float* __restrict__ bih_b, const float* __restrict__ bhh_b,
    unsigned short* __restrict__ y1)
{
    __shared__ short hB_hi[2][1536];   // 96 k x 16 batch, frag order, dbuf

    const int tb  = blockIdx.x & 127;
    const int dir = blockIdx.x >> 7;
    const int b0  = tb << 4;
    const float* wih = dir ? wih_b : wih_f;
    const float* whh = dir ? whh_b : whh_f;
    const float* bih = dir ? bih_b : bih_f;
    const float* bhh = dir ? bhh_b : bhh_f;

    const int tid  = threadIdx.x;
    const int wv   = tid >> 6;
    const int lane = tid & 63;
    const int n    = lane & 15;
    const int quad = lane >> 4;
    const int NT1  = (wv < 2) ? 2 : 1;   // tiles this wave owns

    // ---- W-side (A-operand) preload, hi+lo bf16 ----
    short8 whi[2][3], wlo[2][3];
    const int g_ = n & 3;                               // 0=i 1=f 2=g 3=o
#pragma unroll
    for (int tt = 0; tt < 2; ++tt) {
        if (tt < NT1) {
            const int p  = wv + 16 * tt;
            const int uu = 4 * p + (n >> 2);
#pragma unroll
            for (int q = 0; q < 3; ++q) {
#pragma unroll
                for (int j = 0; j < 8; ++j) {
                    int k = q * 32 + quad * 8 + j;
                    float v = 0.0f;
                    if (uu < H1) {
                        int row = g_ * H1 + uu;
                        if (k < H1)        v = whh[row * H1 + k];
                        else if (k < 80)   v = wih[row * Fz + (k - H1)];
                        else if (k == 80)  v = bih[row] + bhh[row];
                    }
                    unsigned short hi = f2bf(v);
                    unsigned short lo = f2bf(v - bf2f(hi));
                    whi[tt][q][j] = (short)hi;
                    wlo[tt][q][j] = (short)lo;
                }
            }
        }
    }

    // ---- init LDS ----
    for (int e = tid; e < 1536; e += 1024) {
        hB_hi[0][e] = 0; hB_hi[1][e] = 0;
    }
    __syncthreads();
    if (tid < 16) {
        int off = 1280 + tid * 8;       // frag_off(tid, 80)
        hB_hi[0][off] = (short)0x3F80;  // bf16(1.0) bias const
        hB_hi[1][off] = (short)0x3F80;
    }

    // ---- stagers: es in [0,160) -> (m, f), threads 864..1023 ----
    const int es = tid - 864;
    const bool stg = (es >= 0 && es < 160);
    int sm = 0, sf = 0;
    if (stg) { sm = es / Fz; sf = es % Fz; }

    const int tstep = dir ? -1 : 1;
    const int t0    = dir ? (Tz - 1) : 0;

    // prologue: stage x(t0) into buf 0; preload x(t1) into regs
    float xv = 0.0f;
    if (stg) {
        float v = x[((size_t)(b0 + sm) * Tz + t0) * Fz + sf];
        hB_hi[0][frag_off(sm, H1 + sf)] = (short)f2bf(v);
        xv = x[((size_t)(b0 + sm) * Tz + t0 + tstep) * Fz + sf];
    }
    // strided pointers (advance by tstep*stride per step)
    const float* xp = x + ((size_t)(b0 + sm) * Tz + t0 + 2 * tstep) * Fz + sf;
    const ptrdiff_t xinc = (ptrdiff_t)tstep * Fz;
    unsigned short* ypB = y1 + (size_t)(t0 * 128 + tb) * 2304;
    const ptrdiff_t yinc = (ptrdiff_t)tstep * (128 * 2304);

    // hoisted LDS/global write offsets (loop-invariant)
    const int xoff = frag_off(sm, H1 + sf);
    int hoff[2], yoff[2];
#pragma unroll
    for (int tt = 0; tt < 2; ++tt) {
        const int u = 4 * (wv + 16 * tt) + quad;
        hoff[tt] = frag_off(n, u);
        const int K = 32 + dir * H1 + u;               // lstm2 frag k-index
        yoff[tt] = ((K >> 3) * 16 + n) * 8 + (K & 7) - 512;
    }

    float cst[2];
    cst[0] = 0.0f; cst[1] = 0.0f;

    // one step; pp is a literal at each call site -> all LDS addrs invariant
    auto body = [&](int step, const int pp) __attribute__((always_inline)) {
        sync_lds();   // buf[pp] complete, buf[pp^1] free (LDS-only barrier)

        if (stg && step + 1 < Tz) {
            hB_hi[pp ^ 1][xoff] = (short)f2bf(xv);
        }
        if (stg && step + 2 < Tz) {
            xv = *xp;
        }

        short8 bhi[3];
#pragma unroll
        for (int q = 0; q < 3; ++q)
            bhi[q] = *(const short8*)&hB_hi[pp][q * 512 + lane * 8];

        // SPLIT chains: accA (hi, 3-deep) || accB (lo, 3-deep), summed at end
        float4v accA[2], accB[2];
#pragma unroll
        for (int tt = 0; tt < 2; ++tt) {
            accA[tt] = (float4v){0.f, 0.f, 0.f, 0.f};
            accB[tt] = (float4v){0.f, 0.f, 0.f, 0.f};
        }
#pragma unroll
        for (int tt = 0; tt < 2; ++tt) {
            if (tt < NT1) {
                accA[tt] = MFMA16(whi[tt][0], bhi[0], accA[tt]);
                accB[tt] = MFMA16(wlo[tt][0], bhi[0], accB[tt]);
                accA[tt] = MFMA16(whi[tt][1], bhi[1], accA[tt]);
                accB[tt] = MFMA16(wlo[tt][1], bhi[1], accB[tt]);
                accA[tt] = MFMA16(whi[tt][2], bhi[2], accA[tt]);
                accB[tt] = MFMA16(wlo[tt][2], bhi[2], accB[tt]);
            }
        }

#pragma unroll
        for (int tt = 0; tt < 2; ++tt) {
            if (tt < NT1) {
                const int u = 4 * (wv + 16 * tt) + quad;
                if (u < H1) {
                    float h = lstm_gate_h(accA[tt][0] + accB[tt][0],
                                          accA[tt][1] + accB[tt][1],
                                          accA[tt][2] + accB[tt][2],
                                          accA[tt][3] + accB[tt][3], cst[tt]);
                    unsigned short hh = f2bf(h);
                    hB_hi[pp ^ 1][hoff[tt]] = (short)hh;
                    ypB[yoff[tt]] = hh;
                }
            }
        }
        xp  += xinc;
        ypB += yinc;
    };

    for (int step = 0; step < Tz; step += 2) {
        body(step, 0);
        body(step + 1, 1);
    }
}

// ---------------------------------------------------------------------------
// Layer 2 (MFMA, D = W x h): input 140 (bf16 y1 [T][128][2304] FRAG-ORDER),
// hidden 21.  [UNCHANGED r17 version — measured as part of the 573.9us best;
// r18's deeper restructure was neutral, so keep the simpler proven form]
// Grid 256 = 2 dir x 128 tiles of 16 rows. 512 thr = 8 waves: waves 0..5
// compute tile p = wv (u = 4p+quad); threads 224..511 stage x: y1 is
// frag-ordered, so each stager is ONE 16B load + ONE ds_write_b128.
// Stagers es>=272 zero the k=172..175 hole lanes in-register (NaN guard).
// K: 0..20 = h, 21 = bias, 32..171 = x. h/x hi-only; W-lo chunk 0 only:
// 7 MFMA merged chain. r12 gate epilogue. LDS-only barrier, dbuf, prefetch 2.
// ---------------------------------------------------------------------------
__global__ __launch_bounds__(512, 2) void k_lstm2(
    const unsigned short* __restrict__ y1,
    const float* __restrict__ wih_f, const float* __restrict__ whh_f,
    const float* __restrict__ bih_f, const float* __restrict__ bhh_f,
    const float* __restrict__ wih_b, const float* __restrict__ whh_b,
    const float* __restrict__ bih_b, const float* __restrict__ bhh_b,
    unsigned short* __restrict__ y2)   // [B][T][42] bf16
{
    __shared__ short hB_hi[2][3072];   // 192 k x 16 batch

    const int tb  = blockIdx.x & 127;
    const int dir = blockIdx.x >> 7;
    const int b0  = tb << 4;
    const float* wih = dir ? wih_b : wih_f;
    const float* whh = dir ? whh_b : whh_f;
    const float* bih = dir ? bih_b : bih_f;
    const float* bhh = dir ? bhh_b : bhh_f;

    const int tid  = threadIdx.x;
    const int wv   = tid >> 6;
    const int lane = tid & 63;
    const int n    = lane & 15;
    const int quad = lane >> 4;
    const bool comp = (wv < 6);

    // ---- W-side preload (waves 0..5): hi all chunks, lo chunk 0 ----
    short8 whi[6], wlo0;
    const int g_ = n & 3;
    if (comp) {
        const int uu = 4 * wv + (n >> 2);
#pragma unroll
        for (int q = 0; q < 6; ++q) {
#pragma unroll
            for (int j = 0; j < 8; ++j) {
                int k = q * 32 + quad * 8 + j;
                float v = 0.0f;
                if (uu < H2) {
                    int row = g_ * H2 + uu;
                    if (k < H2)                   v = whh[row * H2 + k];
                    else if (k == 21)             v = bih[row] + bhh[row];
                    else if (k >= 32 && k < 172)  v = wih[row * 140 + (k - 32)];
                }
                unsigned short hi = f2bf(v);
                whi[q][j] = (short)hi;
                if (q == 0) wlo0[j] = (short)f2bf(v - bf2f(hi));
            }
        }
    }

    // ---- init LDS ----
    for (int e = tid; e < 3072; e += 512) { hB_hi[0][e] = 0; hB_hi[1][e] = 0; }
    __syncthreads();
    if (tid < 16) {
        int off = frag_off(tid, 21);
        hB_hi[0][off] = (short)0x3F80;   // bias const 1.0
        hB_hi[1][off] = (short)0x3F80;
    }

    // ---- stagers: es in [0,288); threads 224..511; 16B frag-order copy ----
    const int es = tid - 224;
    const bool stg = (es >= 0 && es < 288);
    const bool hole = (es >= 272);       // last k-block: lanes 4..7 = hole

    const int tstep = dir ? -1 : 1;
    const int t0    = dir ? (Tz - 1) : 0;

    // prologue: stage x(t0) into buf 0; preload x(t1)
    short8 xr = (short8){0,0,0,0,0,0,0,0};
    if (stg) {
        short8 v = *(const short8*)(y1 + ((size_t)t0 * 128 + tb) * 2304 + es * 8);
        if (hole) { v[4] = 0; v[5] = 0; v[6] = 0; v[7] = 0; }
        *(short8*)&hB_hi[0][512 + es * 8] = v;
        xr = *(const short8*)(y1 + ((size_t)(t0 + tstep) * 128 + tb) * 2304 + es * 8);
    }
    // strided pointers
    const unsigned short* srcp =
        y1 + ((size_t)(t0 + 2 * tstep) * 128 + tb) * 2304 + es * 8;
    const ptrdiff_t sinc = (ptrdiff_t)tstep * (128 * 2304);
    unsigned short* yp2 = y2 + ((size_t)(b0 + n) * Tz + t0) * 42 + dir * H2;
    const ptrdiff_t yinc = (ptrdiff_t)tstep * 42;

    const int u     = 4 * wv + quad;
    const int hoffc = frag_off(n, (u < H2) ? u : 0);

    float cst = 0.0f;

    auto body = [&](int step, const int pp) __attribute__((always_inline)) {
        sync_lds();   // LDS-only barrier

        if (stg && step + 1 < Tz) {
            short8 v = xr;
            if (hole) { v[4] = 0; v[5] = 0; v[6] = 0; v[7] = 0; }
            *(short8*)&hB_hi[pp ^ 1][512 + es * 8] = v;
        }
        if (stg && step + 2 < Tz) {
            xr = *(const short8*)srcp;
        }

        if (comp) {
            short8 bhi[6];
#pragma unroll
            for (int q = 0; q < 6; ++q)
                bhi[q] = *(const short8*)&hB_hi[pp][q * 512 + lane * 8];

            // merged chain: single acc
            float4v acc = (float4v){0.f, 0.f, 0.f, 0.f};
            acc = MFMA16(whi[0], bhi[0], acc);
            acc = MFMA16(wlo0,   bhi[0], acc);
            acc = MFMA16(whi[1], bhi[1], acc);
            acc = MFMA16(whi[2], bhi[2], acc);
            acc = MFMA16(whi[3], bhi[3], acc);
            acc = MFMA16(whi[4], bhi[4], acc);
            acc = MFMA16(whi[5], bhi[5], acc);

            if (u < H2) {
                float h = lstm_gate_h(acc[0], acc[1], acc[2], acc[3], cst);
                unsigned short hh = f2bf(h);
                hB_hi[pp ^ 1][hoffc] = (short)hh;
                yp2[u] = hh;
            }
        }
        srcp += sinc;
        yp2  += yinc;
    };

    for (int step = 0; step < Tz; step += 2) {
        body(step, 0);
        body(step + 1, 1);
    }
}

// ---------------------------------------------------------------------------
// Dense head: thread per (b,t). Weights via uniform scalar loads.
// ---------------------------------------------------------------------------
__global__ __launch_bounds__(256) void k_dense(
    const unsigned short* __restrict__ y2,
    const float* __restrict__ wd1, const float* __restrict__ bd1,
    const float* __restrict__ wd2, const float* __restrict__ bd2,
    const float* __restrict__ wo,  const float* __restrict__ bo,
    float* __restrict__ out)
{
    int idx = blockIdx.x * 256 + threadIdx.x;
    if (idx >= Bz * Tz) return;
    const unsigned int* row = (const unsigned int*)&y2[(size_t)idx * 42];

    float v[42];
#pragma unroll
    for (int j = 0; j < 21; ++j) {
        unsigned int p = row[j];
        v[2 * j]     = bf2f((unsigned short)(p & 0xFFFFu));
        v[2 * j + 1] = bf2f((unsigned short)(p >> 16));
    }

    float h1[30];
#pragma unroll
    for (int o = 0; o < 30; ++o) {
        float s = bd1[o];
#pragma unroll
        for (int j = 0; j < 42; ++j) s = fmaf(v[j], wd1[o * 42 + j], s);
        h1[o] = fmaxf(s, 0.0f);
    }
    float outv = bo[0];
#pragma unroll
    for (int o = 0; o < 20; ++o) {
        float s = bd2[o];
#pragma unroll
        for (int j = 0; j < 30; ++j) s = fmaf(h1[j], wd2[o * 30 + j], s);
        outv = fmaf(fmaxf(s, 0.0f), wo[o], outv);
    }
    out[idx] = outv;
}

// ---------------------------------------------------------------------------
extern "C" void kernel_launch(void* const* d_in, const int* in_sizes, int n_in,
                              void* d_out, int out_size, void* d_ws, size_t ws_size,
                              hipStream_t stream)
{
    const float* x      = (const float*)d_in[0];
    const float* w1f_ih = (const float*)d_in[1];
    const float* w1f_hh = (const float*)d_in[2];
    const float* b1f_ih = (const float*)d_in[3];
    const float* b1f_hh = (const float*)d_in[4];
    const float* w1b_ih = (const float*)d_in[5];
    const float* w1b_hh = (const float*)d_in[6];
    const float* b1b_ih = (const float*)d_in[7];
    const float* b1b_hh = (const float*)d_in[8];
    const float* w2f_ih = (const float*)d_in[9];
    const float* w2f_hh = (const float*)d_in[10];
    const float* b2f_ih = (const float*)d_in[11];
    const float* b2f_hh = (const float*)d_in[12];
    const float* w2b_ih = (const float*)d_in[13];
    const float* w2b_hh = (const float*)d_in[14];
    const float* b2b_ih = (const float*)d_in[15];
    const float* b2b_hh = (const float*)d_in[16];
    const float* wd1    = (const float*)d_in[17];
    const float* bd1    = (const float*)d_in[18];
    const float* wd2    = (const float*)d_in[19];
    const float* bd2    = (const float*)d_in[20];
    const float* wo     = (const float*)d_in[21];
    const float* bo     = (const float*)d_in[22];
    float* out = (float*)d_out;

    // Workspace: y1 bf16 [T][128][2304] frag-order (198.2 MB)
    //          + y2 bf16 [B][T][42] (57.8 MB)
    const size_t y1_elems = (size_t)Tz * 128 * 2304;
    const size_t y2_elems = (size_t)Bz * Tz * 42;
    if (ws_size < (y1_elems + y2_elems) * 2) return;

    unsigned short* y1 = (unsigned short*)d_ws;
    unsigned short* y2 = y1 + y1_elems;

    hipLaunchKernelGGL(k_lstm1, dim3(256), dim3(1024), 0, stream,
                       x, w1f_ih, w1f_hh, b1f_ih, b1f_hh,
                       w1b_ih, w1b_hh, b1b_ih, b1b_hh, y1);
    hipLaunchKernelGGL(k_lstm2, dim3(256), dim3(512), 0, stream,
                       y1, w2f_ih, w2f_hh, b2f_ih, b2f_hh,
                       w2b_ih, w2b_hh, b2b_ih, b2b_hh, y2);
    hipLaunchKernelGGL(k_dense, dim3((Bz * Tz + 255) / 256), dim3(256), 0, stream,
                       y2, wd1, bd1, wd2, bd2, wo, bo, out);
}

// Round 20
// 574.803 us; speedup vs baseline: 1.0165x; 1.0106x over previous
//
#include <hip/hip_runtime.h>

// Problem constants
#define Bz 2048
#define Tz 336
#define Fz 10
#define H1 70
#define H2 21

typedef __attribute__((ext_vector_type(8))) short short8;   // 8 bf16 = 4 VGPR
typedef __attribute__((ext_vector_type(4))) float float4v;  // MFMA acc

#define MFMA16(a, b, c) __builtin_amdgcn_mfma_f32_16x16x32_bf16((a), (b), (c), 0, 0, 0)

// LDS-only barrier (composable-kernel idiom): orders LDS across the block
// WITHOUT draining vmcnt — __syncthreads() would stall on the y1/y2 global
// stores (never read in-kernel) every step (~200-900 cyc store-ack, m126).
__device__ __forceinline__ void sync_lds() {
    asm volatile("s_waitcnt lgkmcnt(0)\n\ts_barrier" ::: "memory");
}

// Manual RNE f32->bf16 (validated). r14: v_cvt_pk_bf16_f32 regressed absmax
// 10x (biased rounding compounds through the 336-step recurrence).
__device__ __forceinline__ unsigned short f2bf(float v) {
    unsigned int u = __float_as_uint(v);
    u += 0x7FFFu + ((u >> 16) & 1u);
    return (unsigned short)(u >> 16);
}
__device__ __forceinline__ float bf2f(unsigned short s) {
    return __uint_as_float(((unsigned int)s) << 16);
}

// [r12-VALIDATED gate epilogue — exp-domain, true division.]
// Session ledger: exp2-domain weights + raw v_rcp (r13/r14) regressed absmax
// to ~9e-3 — RETIRED. cvt_pk bf16 — RETIRED (r14, 10x absmax). Split MFMA
// chain (r19) — neutral-negative, REVERTED. This form measured 0.98e-3.
//   cn = sig(f)*c + sig(i)*tanh(g);  h = sig(o)*tanh(cn)
// via a=e^-f, b=e^-i, d=e^2g:  cn = (c*pb*pd + pa*(d-1)) / (pa*pb*pd)
// 5 exp + 2 true divisions (common-denominator form).
__device__ __forceinline__ float lstm_gate_h(float gi, float gf, float gc,
                                             float go, float& cst) {
    float a  = __expf(-gf);
    float b  = __expf(-gi);
    float d  = __expf(2.0f * gc);
    float pa = 1.0f + a;
    float pb = 1.0f + b;
    float pd = d + 1.0f;
    float t1 = pb * pd;
    float num = fmaf(pa, d - 1.0f, cst * t1);
    float cn  = num / (pa * t1);
    float e2  = __expf(-go);
    float f2  = __expf(2.0f * cn);
    float h   = (f2 - 1.0f) / ((1.0f + e2) * (f2 + 1.0f));
    cst = cn;
    return h;
}

// Fragment-order LDS offset (in shorts) for (col m, k):
// (m, k) lives at ((k>>3)*16 + m)*8 + (k&7)
__device__ __forceinline__ int frag_off(int m, int k) {
    return (k >> 3) * 128 + m * 8 + (k & 7);
}

// ---------------------------------------------------------------------------
// Layer 1 (MFMA, D = W x h): input F=10, hidden 70.
// [EXACT r17 configuration — measured 296.4 us / total 573.9 us, best]
// Grid 256 = 2 dir x 128 tiles of 16 batch rows. 1024 threads = 16 waves.
// 18 M-tiles: wave w owns tile w; waves 0,1 also own tiles 16,17.
//   K: 0..69 = h, 70..79 = x, 80 = bias slot (B col 1.0), 81..95 = 0.
// h bf16 hi-only in LDS; W hi+lo in registers; merged 6-MFMA chain (r19's
// split was neutral-negative -> merged form restored). ONE LDS-only barrier
// per step, double-buffered B-LDS, x prefetch depth 2, x2 unroll (pp
// literal), strided pointers.
// y1 layout: [T][128][2304] bf16, frag-ordered for k=32..171 (slot =
// frag_off(n, 32+dir*70+u) - 512); k=172..175 slots are holes (lstm2 zeros).
// ---------------------------------------------------------------------------
__global__ __launch_bounds__(1024, 4) void k_lstm1(
    const float* __restrict__ x,
    const float* __restrict__ wih_f, const float* __restrict__ whh_f,
    const float* __restrict__ bih_f, const float* __restrict__ bhh_f,
    const float* __restrict__ wih_b, const float* __restrict__ whh_b,
    const float* __restrict__ bih_b, const float* __restrict__ bhh_b,
    unsigned short* __restrict__ y1)
{
    __shared__ short hB_hi[2][1536];   // 96 k x 16 batch, frag order, dbuf

    const int tb  = blockIdx.x & 127;
    const int dir = blockIdx.x >> 7;
    const int b0  = tb << 4;
    const float* wih = dir ? wih_b : wih_f;
    const float* whh = dir ? whh_b : whh_f;
    const float* bih = dir ? bih_b : bih_f;
    const float* bhh = dir ? bhh_b : bhh_f;

    const int tid  = threadIdx.x;
    const int wv   = tid >> 6;
    const int lane = tid & 63;
    const int n    = lane & 15;
    const int quad = lane >> 4;
    const int NT1  = (wv < 2) ? 2 : 1;   // tiles this wave owns

    // ---- W-side (A-operand) preload, hi+lo bf16 ----
    short8 whi[2][3], wlo[2][3];
    const int g_ = n & 3;                               // 0=i 1=f 2=g 3=o
#pragma unroll
    for (int tt = 0; tt < 2; ++tt) {
        if (tt < NT1) {
            const int p  = wv + 16 * tt;
            const int uu = 4 * p + (n >> 2);
#pragma unroll
            for (int q = 0; q < 3; ++q) {
#pragma unroll
                for (int j = 0; j < 8; ++j) {
                    int k = q * 32 + quad * 8 + j;
                    float v = 0.0f;
                    if (uu < H1) {
                        int row = g_ * H1 + uu;
                        if (k < H1)        v = whh[row * H1 + k];
                        else if (k < 80)   v = wih[row * Fz + (k - H1)];
                        else if (k == 80)  v = bih[row] + bhh[row];
                    }
                    unsigned short hi = f2bf(v);
                    unsigned short lo = f2bf(v - bf2f(hi));
                    whi[tt][q][j] = (short)hi;
                    wlo[tt][q][j] = (short)lo;
                }
            }
        }
    }

    // ---- init LDS ----
    for (int e = tid; e < 1536; e += 1024) {
        hB_hi[0][e] = 0; hB_hi[1][e] = 0;
    }
    __syncthreads();
    if (tid < 16) {
        int off = 1280 + tid * 8;       // frag_off(tid, 80)
        hB_hi[0][off] = (short)0x3F80;  // bf16(1.0) bias const
        hB_hi[1][off] = (short)0x3F80;
    }

    // ---- stagers: es in [0,160) -> (m, f), threads 864..1023 ----
    const int es = tid - 864;
    const bool stg = (es >= 0 && es < 160);
    int sm = 0, sf = 0;
    if (stg) { sm = es / Fz; sf = es % Fz; }

    const int tstep = dir ? -1 : 1;
    const int t0    = dir ? (Tz - 1) : 0;

    // prologue: stage x(t0) into buf 0; preload x(t1) into regs
    float xv = 0.0f;
    if (stg) {
        float v = x[((size_t)(b0 + sm) * Tz + t0) * Fz + sf];
        hB_hi[0][frag_off(sm, H1 + sf)] = (short)f2bf(v);
        xv = x[((size_t)(b0 + sm) * Tz + t0 + tstep) * Fz + sf];
    }
    // strided pointers (advance by tstep*stride per step)
    const float* xp = x + ((size_t)(b0 + sm) * Tz + t0 + 2 * tstep) * Fz + sf;
    const ptrdiff_t xinc = (ptrdiff_t)tstep * Fz;
    unsigned short* ypB = y1 + (size_t)(t0 * 128 + tb) * 2304;
    const ptrdiff_t yinc = (ptrdiff_t)tstep * (128 * 2304);

    // hoisted LDS/global write offsets (loop-invariant)
    const int xoff = frag_off(sm, H1 + sf);
    int hoff[2], yoff[2];
#pragma unroll
    for (int tt = 0; tt < 2; ++tt) {
        const int u = 4 * (wv + 16 * tt) + quad;
        hoff[tt] = frag_off(n, u);
        const int K = 32 + dir * H1 + u;               // lstm2 frag k-index
        yoff[tt] = ((K >> 3) * 16 + n) * 8 + (K & 7) - 512;
    }

    float cst[2];
    cst[0] = 0.0f; cst[1] = 0.0f;

    // one step; pp is a literal at each call site -> all LDS addrs invariant
    auto body = [&](int step, const int pp) __attribute__((always_inline)) {
        sync_lds();   // buf[pp] complete, buf[pp^1] free (LDS-only barrier)

        if (stg && step + 1 < Tz) {
            hB_hi[pp ^ 1][xoff] = (short)f2bf(xv);
        }
        if (stg && step + 2 < Tz) {
            xv = *xp;
        }

        short8 bhi[3];
#pragma unroll
        for (int q = 0; q < 3; ++q)
            bhi[q] = *(const short8*)&hB_hi[pp][q * 512 + lane * 8];

        // merged hi/lo chain: single acc per tile
        float4v acc[2];
#pragma unroll
        for (int tt = 0; tt < 2; ++tt) acc[tt] = (float4v){0.f, 0.f, 0.f, 0.f};
#pragma unroll
        for (int tt = 0; tt < 2; ++tt) {
            if (tt < NT1) {
                acc[tt] = MFMA16(whi[tt][0], bhi[0], acc[tt]);
                acc[tt] = MFMA16(wlo[tt][0], bhi[0], acc[tt]);
                acc[tt] = MFMA16(whi[tt][1], bhi[1], acc[tt]);
                acc[tt] = MFMA16(wlo[tt][1], bhi[1], acc[tt]);
                acc[tt] = MFMA16(whi[tt][2], bhi[2], acc[tt]);
                acc[tt] = MFMA16(wlo[tt][2], bhi[2], acc[tt]);
            }
        }

#pragma unroll
        for (int tt = 0; tt < 2; ++tt) {
            if (tt < NT1) {
                const int u = 4 * (wv + 16 * tt) + quad;
                if (u < H1) {
                    float h = lstm_gate_h(acc[tt][0], acc[tt][1],
                                          acc[tt][2], acc[tt][3], cst[tt]);
                    unsigned short hh = f2bf(h);
                    hB_hi[pp ^ 1][hoff[tt]] = (short)hh;
                    ypB[yoff[tt]] = hh;
                }
            }
        }
        xp  += xinc;
        ypB += yinc;
    };

    for (int step = 0; step < Tz; step += 2) {
        body(step, 0);
        body(step + 1, 1);
    }
}

// ---------------------------------------------------------------------------
// Layer 2 (MFMA, D = W x h): input 140 (bf16 y1 [T][128][2304] FRAG-ORDER),
// hidden 21.  [EXACT r17 version — part of the 573.9us best; r18's
// dependency-chain removal was neutral, so this simpler form stands]
// Grid 256 = 2 dir x 128 tiles of 16 rows. 512 thr = 8 waves: waves 0..5
// compute tile p = wv (u = 4p+quad); threads 224..511 stage x: y1 is
// frag-ordered, so each stager is ONE 16B load + ONE ds_write_b128.
// Stagers es>=272 zero the k=172..175 hole lanes in-register (NaN guard).
// K: 0..20 = h, 21 = bias, 32..171 = x. h/x hi-only; W-lo chunk 0 only:
// 7 MFMA merged chain. r12 gate epilogue. LDS-only barrier, dbuf, prefetch 2.
// ---------------------------------------------------------------------------
__global__ __launch_bounds__(512, 2) void k_lstm2(
    const unsigned short* __restrict__ y1,
    const float* __restrict__ wih_f, const float* __restrict__ whh_f,
    const float* __restrict__ bih_f, const float* __restrict__ bhh_f,
    const float* __restrict__ wih_b, const float* __restrict__ whh_b,
    const float* __restrict__ bih_b, const float* __restrict__ bhh_b,
    unsigned short* __restrict__ y2)   // [B][T][42] bf16
{
    __shared__ short hB_hi[2][3072];   // 192 k x 16 batch

    const int tb  = blockIdx.x & 127;
    const int dir = blockIdx.x >> 7;
    const int b0  = tb << 4;
    const float* wih = dir ? wih_b : wih_f;
    const float* whh = dir ? whh_b : whh_f;
    const float* bih = dir ? bih_b : bih_f;
    const float* bhh = dir ? bhh_b : bhh_f;

    const int tid  = threadIdx.x;
    const int wv   = tid >> 6;
    const int lane = tid & 63;
    const int n    = lane & 15;
    const int quad = lane >> 4;
    const bool comp = (wv < 6);

    // ---- W-side preload (waves 0..5): hi all chunks, lo chunk 0 ----
    short8 whi[6], wlo0;
    const int g_ = n & 3;
    if (comp) {
        const int uu = 4 * wv + (n >> 2);
#pragma unroll
        for (int q = 0; q < 6; ++q) {
#pragma unroll
            for (int j = 0; j < 8; ++j) {
                int k = q * 32 + quad * 8 + j;
                float v = 0.0f;
                if (uu < H2) {
                    int row = g_ * H2 + uu;
                    if (k < H2)                   v = whh[row * H2 + k];
                    else if (k == 21)             v = bih[row] + bhh[row];
                    else if (k >= 32 && k < 172)  v = wih[row * 140 + (k - 32)];
                }
                unsigned short hi = f2bf(v);
                whi[q][j] = (short)hi;
                if (q == 0) wlo0[j] = (short)f2bf(v - bf2f(hi));
            }
        }
    }

    // ---- init LDS ----
    for (int e = tid; e < 3072; e += 512) { hB_hi[0][e] = 0; hB_hi[1][e] = 0; }
    __syncthreads();
    if (tid < 16) {
        int off = frag_off(tid, 21);
        hB_hi[0][off] = (short)0x3F80;   // bias const 1.0
        hB_hi[1][off] = (short)0x3F80;
    }

    // ---- stagers: es in [0,288); threads 224..511; 16B frag-order copy ----
    const int es = tid - 224;
    const bool stg = (es >= 0 && es < 288);
    const bool hole = (es >= 272);       // last k-block: lanes 4..7 = hole

    const int tstep = dir ? -1 : 1;
    const int t0    = dir ? (Tz - 1) : 0;

    // prologue: stage x(t0) into buf 0; preload x(t1)
    short8 xr = (short8){0,0,0,0,0,0,0,0};
    if (stg) {
        short8 v = *(const short8*)(y1 + ((size_t)t0 * 128 + tb) * 2304 + es * 8);
        if (hole) { v[4] = 0; v[5] = 0; v[6] = 0; v[7] = 0; }
        *(short8*)&hB_hi[0][512 + es * 8] = v;
        xr = *(const short8*)(y1 + ((size_t)(t0 + tstep) * 128 + tb) * 2304 + es * 8);
    }
    // strided pointers
    const unsigned short* srcp =
        y1 + ((size_t)(t0 + 2 * tstep) * 128 + tb) * 2304 + es * 8;
    const ptrdiff_t sinc = (ptrdiff_t)tstep * (128 * 2304);
    unsigned short* yp2 = y2 + ((size_t)(b0 + n) * Tz + t0) * 42 + dir * H2;
    const ptrdiff_t yinc = (ptrdiff_t)tstep * 42;

    const int u     = 4 * wv + quad;
    const int hoffc = frag_off(n, (u < H2) ? u : 0);

    float cst = 0.0f;

    auto body = [&](int step, const int pp) __attribute__((always_inline)) {
        sync_lds();   // LDS-only barrier

        if (stg && step + 1 < Tz) {
            short8 v = xr;
            if (hole) { v[4] = 0; v[5] = 0; v[6] = 0; v[7] = 0; }
            *(short8*)&hB_hi[pp ^ 1][512 + es * 8] = v;
        }
        if (stg && step + 2 < Tz) {
            xr = *(const short8*)srcp;
        }

        if (comp) {
            short8 bhi[6];
#pragma unroll
            for (int q = 0; q < 6; ++q)
                bhi[q] = *(const short8*)&hB_hi[pp][q * 512 + lane * 8];

            // merged chain: single acc
            float4v acc = (float4v){0.f, 0.f, 0.f, 0.f};
            acc = MFMA16(whi[0], bhi[0], acc);
            acc = MFMA16(wlo0,   bhi[0], acc);
            acc = MFMA16(whi[1], bhi[1], acc);
            acc = MFMA16(whi[2], bhi[2], acc);
            acc = MFMA16(whi[3], bhi[3], acc);
            acc = MFMA16(whi[4], bhi[4], acc);
            acc = MFMA16(whi[5], bhi[5], acc);

            if (u < H2) {
                float h = lstm_gate_h(acc[0], acc[1], acc[2], acc[3], cst);
                unsigned short hh = f2bf(h);
                hB_hi[pp ^ 1][hoffc] = (short)hh;
                yp2[u] = hh;
            }
        }
        srcp += sinc;
        yp2  += yinc;
    };

    for (int step = 0; step < Tz; step += 2) {
        body(step, 0);
        body(step + 1, 1);
    }
}

// ---------------------------------------------------------------------------
// Dense head: thread per (b,t). Weights via uniform scalar loads.
// ---------------------------------------------------------------------------
__global__ __launch_bounds__(256) void k_dense(
    const unsigned short* __restrict__ y2,
    const float* __restrict__ wd1, const float* __restrict__ bd1,
    const float* __restrict__ wd2, const float* __restrict__ bd2,
    const float* __restrict__ wo,  const float* __restrict__ bo,
    float* __restrict__ out)
{
    int idx = blockIdx.x * 256 + threadIdx.x;
    if (idx >= Bz * Tz) return;
    const unsigned int* row = (const unsigned int*)&y2[(size_t)idx * 42];

    float v[42];
#pragma unroll
    for (int j = 0; j < 21; ++j) {
        unsigned int p = row[j];
        v[2 * j]     = bf2f((unsigned short)(p & 0xFFFFu));
        v[2 * j + 1] = bf2f((unsigned short)(p >> 16));
    }

    float h1[30];
#pragma unroll
    for (int o = 0; o < 30; ++o) {
        float s = bd1[o];
#pragma unroll
        for (int j = 0; j < 42; ++j) s = fmaf(v[j], wd1[o * 42 + j], s);
        h1[o] = fmaxf(s, 0.0f);
    }
    float outv = bo[0];
#pragma unroll
    for (int o = 0; o < 20; ++o) {
        float s = bd2[o];
#pragma unroll
        for (int j = 0; j < 30; ++j) s = fmaf(h1[j], wd2[o * 30 + j], s);
        outv = fmaf(fmaxf(s, 0.0f), wo[o], outv);
    }
    out[idx] = outv;
}

// ---------------------------------------------------------------------------
extern "C" void kernel_launch(void* const* d_in, const int* in_sizes, int n_in,
                              void* d_out, int out_size, void* d_ws, size_t ws_size,
                              hipStream_t stream)
{
    const float* x      = (const float*)d_in[0];
    const float* w1f_ih = (const float*)d_in[1];
    const float* w1f_hh = (const float*)d_in[2];
    const float* b1f_ih = (const float*)d_in[3];
    const float* b1f_hh = (const float*)d_in[4];
    const float* w1b_ih = (const float*)d_in[5];
    const float* w1b_hh = (const float*)d_in[6];
    const float* b1b_ih = (const float*)d_in[7];
    const float* b1b_hh = (const float*)d_in[8];
    const float* w2f_ih = (const float*)d_in[9];
    const float* w2f_hh = (const float*)d_in[10];
    const float* b2f_ih = (const float*)d_in[11];
    const float* b2f_hh = (const float*)d_in[12];
    const float* w2b_ih = (const float*)d_in[13];
    const float* w2b_hh = (const float*)d_in[14];
    const float* b2b_ih = (const float*)d_in[15];
    const float* b2b_hh = (const float*)d_in[16];
    const float* wd1    = (const float*)d_in[17];
    const float* bd1    = (const float*)d_in[18];
    const float* wd2    = (const float*)d_in[19];
    const float* bd2    = (const float*)d_in[20];
    const float* wo     = (const float*)d_in[21];
    const float* bo     = (const float*)d_in[22];
    float* out = (float*)d_out;

    // Workspace: y1 bf16 [T][128][2304] frag-order (198.2 MB)
    //          + y2 bf16 [B][T][42] (57.8 MB)
    const size_t y1_elems = (size_t)Tz * 128 * 2304;
    const size_t y2_elems = (size_t)Bz * Tz * 42;
    if (ws_size < (y1_elems + y2_elems) * 2) return;

    unsigned short* y1 = (unsigned short*)d_ws;
    unsigned short* y2 = y1 + y1_elems;

    hipLaunchKernelGGL(k_lstm1, dim3(256), dim3(1024), 0, stream,
                       x, w1f_ih, w1f_hh, b1f_ih, b1f_hh,
                       w1b_ih, w1b_hh, b1b_ih, b1b_hh, y1);
    hipLaunchKernelGGL(k_lstm2, dim3(256), dim3(512), 0, stream,
                       y1, w2f_ih, w2f_hh, b2f_ih, b2f_hh,
                       w2b_ih, w2b_hh, b2b_ih, b2b_hh, y2);
    hipLaunchKernelGGL(k_dense, dim3((Bz * Tz + 255) / 256), dim3(256), 0, stream,
                       y2, wd1, bd1, wd2, bd2, wo, bo, out);
}